// Round 2
// baseline (461.169 us; speedup 1.0000x reference)
//
#include <hip/hip_runtime.h>

// Batched 8x8 DCT: out = M^T * img * M + 128, M[i][j] = 0.5*a[i]*cos((2j+1)*i*pi/16)
//   a[i]   = alpha[i*8+1]        (alpha = outer(a,a), a[1]==1)
//   C[i][j]= dct[i*512 + j*8]    (dct_tensor[i,0,j,0], cos(0)==1 factor)
//
// Row-per-lane design: 8 lanes per block, lane owns one 8-float row.
//   - global load/store: thread t <-> floats [tile*2048 + t*8, +8) -- coalesced
//   - middle transpose of the separable transform done in registers via
//     3-stage __shfl_xor butterfly (masks 1,2,4 stay inside the 8-lane group)
//   - zero LDS, zero barriers -> occupancy limited only by VGPRs

#define WG   256   // 32 blocks per WG-iteration
#define GRID 2048  // persistent-ish grid; grid-stride over tiles

__device__ __forceinline__ void transpose8(float a[8], int lane8) {
    // After this, lane L's a[j] == (original lane j's a[L]) within each 8-lane group.
#pragma unroll
    for (int m = 1; m <= 4; m <<= 1) {
        const bool up = (lane8 & m) != 0;
#pragma unroll
        for (int j = 0; j < 8; ++j) {
            if ((j & m) == 0) {
                float send = up ? a[j] : a[j ^ m];
                float recv = __shfl_xor(send, m, 64);
                if (up) a[j] = recv; else a[j ^ m] = recv;
            }
        }
    }
}

__global__ __launch_bounds__(WG, 4) void dct8x8_kernel(
    const float* __restrict__ image,
    const float* __restrict__ alpha,
    const float* __restrict__ dct,
    float* __restrict__ out,
    int nblocks)
{
    // ---- uniform M matrix (scalar loads; uniform across lanes) ----
    float M[8][8];
#pragma unroll
    for (int i = 0; i < 8; ++i) {
        const float ai = 0.5f * alpha[i * 8 + 1];
#pragma unroll
        for (int j = 0; j < 8; ++j)
            M[i][j] = ai * dct[i * 512 + j * 8];
    }

    const int t = threadIdx.x;        // 0..255
    const int lane8 = t & 7;          // row index within this thread's block
    const long long tiles = ((long long)nblocks + (WG / 8) - 1) / (WG / 8);

    for (long long tile = blockIdx.x; tile < tiles; tile += gridDim.x) {
        const long long gb = tile * (WG / 8) + (t >> 3);   // global block index
        const bool valid = gb < (long long)nblocks;

        // ---- load my row (2x float4, lanes stride 32B -> fully coalesced) ----
        float a[8];
        const float4* in4 = (const float4*)image + tile * (WG * 2) + t * 2;
        if (valid) {
            float4 lo = in4[0];
            float4 hi = in4[1];
            a[0] = lo.x; a[1] = lo.y; a[2] = lo.z; a[3] = lo.w;
            a[4] = hi.x; a[5] = hi.y; a[6] = hi.z; a[7] = hi.w;
        } else {
#pragma unroll
            for (int j = 0; j < 8; ++j) a[j] = 0.0f;
        }

        // ---- stage 1: P[v] = sum_y a[y] * M[y][v]   (P row x = lane8) ----
        float P[8];
#pragma unroll
        for (int v = 0; v < 8; ++v) {
            float acc = 0.0f;
#pragma unroll
            for (int y = 0; y < 8; ++y)
                acc = fmaf(a[y], M[y][v], acc);
            P[v] = acc;
        }

        // ---- register transpose: lane c now holds column c: P[x][c], x=0..7 ----
        transpose8(P, lane8);

        // ---- stage 2: O[u] = 128 + sum_x M[x][u] * P[x]  (out column c) ----
        float O[8];
#pragma unroll
        for (int u = 0; u < 8; ++u) {
            float acc = 128.0f;
#pragma unroll
            for (int x = 0; x < 8; ++x)
                acc = fmaf(M[x][u], P[x], acc);
            O[u] = acc;
        }

        // ---- transpose back: lane r holds out row r ----
        transpose8(O, lane8);

        // ---- store my row (coalesced, same mapping as load) ----
        if (valid) {
            float4* o4 = (float4*)out + tile * (WG * 2) + t * 2;
            o4[0] = make_float4(O[0], O[1], O[2], O[3]);
            o4[1] = make_float4(O[4], O[5], O[6], O[7]);
        }
    }
}

extern "C" void kernel_launch(void* const* d_in, const int* in_sizes, int n_in,
                              void* d_out, int out_size, void* d_ws, size_t ws_size,
                              hipStream_t stream) {
    const float* image = (const float*)d_in[0];
    const float* alpha = (const float*)d_in[1];
    const float* dct   = (const float*)d_in[2];
    float* outp = (float*)d_out;

    const int nblocks = in_sizes[0] / 64;
    const long long tiles = ((long long)nblocks + (WG / 8) - 1) / (WG / 8);
    int grid = (int)((tiles < GRID) ? tiles : GRID);
    if (grid < 1) grid = 1;

    dct8x8_kernel<<<grid, WG, 0, stream>>>(image, alpha, dct, outp, nblocks);
}

// Round 3
// 355.402 us; speedup vs baseline: 1.2976x; 1.2976x over previous
//
#include <hip/hip_runtime.h>

// Batched 8x8 DCT: out = M^T * img * M + 128
//   M[i][j] = 0.5 * a[i] * cos((2j+1)*i*pi/16)
//   a[i]    = alpha[i*8+1]       (alpha = outer(a,a), a[1]==1)
//   C[i][j] = dct[i*512 + j*8]   (dct_tensor[i,0,j,0]; cos(0)==1)
//
// Design: one 8x8 block per thread. No LDS, no shuffles, no barriers.
//   - loads/stores: 16 dwordx4 per thread, contiguous 256B per lane
//     (strided across lanes, but every fetched line fully consumed)
//   - M broadcast to SGPRs via v_readlane -> VALU ops use SGPR operand
//   - per-row interleave keeps live VGPRs ~ rows + acc (fits 128 cap)

#define WG 256

__global__ __launch_bounds__(WG, 4) void dct8x8_kernel(
    const float* __restrict__ image,
    const float* __restrict__ alpha,
    const float* __restrict__ dct,
    float* __restrict__ out,
    int nblocks)
{
    const int t = threadIdx.x;
    const int lane = t & 63;

    // ---- M element per lane, then broadcast all 64 into SGPRs ----
    float mv;
    {
        const int i = lane >> 3, j = lane & 7;
        mv = 0.5f * alpha[i * 8 + 1] * dct[i * 512 + j * 8];
    }
    float M[64];
#pragma unroll
    for (int k = 0; k < 64; ++k)
        M[k] = __int_as_float(__builtin_amdgcn_readlane(__float_as_int(mv), k));

    const long long gb = (long long)blockIdx.x * WG + t;   // my 8x8 block
    if (gb >= nblocks) return;

    const float4* __restrict__ in4  = (const float4*)image + (size_t)gb * 16;
    float4*       __restrict__ out4 = (float4*)out         + (size_t)gb * 16;

    // ---- fused: per input row x, stage1 then accumulate into acc ----
    //   b1[v]      = sum_y row[y] * M[y][v]
    //   acc[u][v] += M[x][u] * b1[v]      (init 128)
    float acc[8][8];
#pragma unroll
    for (int u = 0; u < 8; ++u)
#pragma unroll
        for (int v = 0; v < 8; ++v)
            acc[u][v] = 128.0f;

#pragma unroll
    for (int x = 0; x < 8; ++x) {
        const float4 lo = in4[x * 2 + 0];
        const float4 hi = in4[x * 2 + 1];
        float row[8] = {lo.x, lo.y, lo.z, lo.w, hi.x, hi.y, hi.z, hi.w};

        float b1[8];
#pragma unroll
        for (int v = 0; v < 8; ++v) {
            float s = 0.0f;
#pragma unroll
            for (int y = 0; y < 8; ++y)
                s = fmaf(row[y], M[y * 8 + v], s);
            b1[v] = s;
        }
#pragma unroll
        for (int u = 0; u < 8; ++u) {
            const float mu = M[x * 8 + u];
#pragma unroll
            for (int v = 0; v < 8; ++v)
                acc[u][v] = fmaf(mu, b1[v], acc[u][v]);
        }
    }

    // ---- store my block: 16 dwordx4, contiguous 256B ----
#pragma unroll
    for (int q = 0; q < 16; ++q) {
        const int u = q >> 1, vb = (q & 1) * 4;
        out4[q] = make_float4(acc[u][vb + 0], acc[u][vb + 1],
                              acc[u][vb + 2], acc[u][vb + 3]);
    }
}

extern "C" void kernel_launch(void* const* d_in, const int* in_sizes, int n_in,
                              void* d_out, int out_size, void* d_ws, size_t ws_size,
                              hipStream_t stream) {
    const float* image = (const float*)d_in[0];
    const float* alpha = (const float*)d_in[1];
    const float* dct   = (const float*)d_in[2];
    float* outp = (float*)d_out;

    const int nblocks = in_sizes[0] / 64;
    const int grid = (nblocks + WG - 1) / WG;

    dct8x8_kernel<<<grid, WG, 0, stream>>>(image, alpha, dct, outp, nblocks);
}

// Round 4
// 220.303 us; speedup vs baseline: 2.0933x; 1.6132x over previous
//
#include <hip/hip_runtime.h>

// Batched 8x8 iDCT: out = M^T * img * M + 128
//   M[i][j] = 0.5 * a[i] * cos((2j+1)*i*pi/16)
//   a[i]    = alpha[i*8+1]       (alpha = outer(a,a), a[1]==1)
//   cos term = dct[i*512 + j*8]  (dct_tensor[i,0,j,0]; cos(0)==1)
//
// Design E: 8 lanes per block, lane owns one row.
//   - global load/store: 2x dwordx4 per lane, 32B contiguous -> coalesced, exact traffic
//   - stage1 (row transform) fully in-register with uniform M in SGPRs
//   - intermediate P staged in LDS: 2 ds_write_b128 + 16 ds_read_b128 (broadcast) per lane
//     block stride 17*float4 => all 8 quad-bank groups hit evenly, zero conflicts
//   - stage2 weights M[x][r] (runtime lane row r) loaded per-lane (8 L1-hit loads)
//   - 8.7KB LDS, ~45 VGPR -> 8 waves/SIMD

#define WG      256
#define BPW     (WG / 8)      // 32 blocks per workgroup
#define STRIDE4 17            // float4 stride per block in LDS (odd -> conflict-free)

__global__ __launch_bounds__(WG, 8) void dct8x8_kernel(
    const float* __restrict__ image,
    const float* __restrict__ alpha,
    const float* __restrict__ dct,
    float* __restrict__ out,
    int nblocks)
{
    __shared__ float4 lds4[BPW * STRIDE4];   // 32*17*16B = 8704 B

    const int t = threadIdx.x;
    const int b = t >> 3;          // local block 0..31
    const int r = t & 7;           // my row / output row u

    // ---- stage-1 matrix: uniform across lanes -> SGPRs ----
    float M[8][8];
#pragma unroll
    for (int i = 0; i < 8; ++i) {
        const float ai = 0.5f * alpha[i * 8 + 1];
#pragma unroll
        for (int j = 0; j < 8; ++j)
            M[i][j] = ai * dct[i * 512 + j * 8];
    }

    // ---- stage-2 weights M[x][r]: runtime r -> per-lane vector loads (L1-hit) ----
    float mu[8];
#pragma unroll
    for (int x = 0; x < 8; ++x)
        mu[x] = 0.5f * alpha[x * 8 + 1] * dct[x * 512 + r * 8];

    const long long gblk = (long long)blockIdx.x * BPW + b;
    const bool valid = gblk < (long long)nblocks;
    const size_t base4 = (size_t)gblk * 16 + (size_t)r * 2;

    // ---- load my row: 32B contiguous, lanes stride 32B -> coalesced ----
    float row[8];
    if (valid) {
        const float4 lo = ((const float4*)image)[base4 + 0];
        const float4 hi = ((const float4*)image)[base4 + 1];
        row[0] = lo.x; row[1] = lo.y; row[2] = lo.z; row[3] = lo.w;
        row[4] = hi.x; row[5] = hi.y; row[6] = hi.z; row[7] = hi.w;
    } else {
#pragma unroll
        for (int j = 0; j < 8; ++j) row[j] = 0.0f;
    }

    // ---- stage 1: P[v] = sum_y row[y] * M[y][v]  (P row index = r) ----
    float P[8];
#pragma unroll
    for (int v = 0; v < 8; ++v) {
        float s = 0.0f;
#pragma unroll
        for (int y = 0; y < 8; ++y)
            s = fmaf(row[y], M[y][v], s);
        P[v] = s;
    }

    // ---- stage P row to LDS (2x ds_write_b128, conflict-free) ----
    lds4[b * STRIDE4 + r * 2 + 0] = make_float4(P[0], P[1], P[2], P[3]);
    lds4[b * STRIDE4 + r * 2 + 1] = make_float4(P[4], P[5], P[6], P[7]);
    __syncthreads();

    // ---- stage 2: O[v] = 128 + sum_x mu[x] * P[x][v]  (broadcast reads) ----
    float O[8] = {128.0f, 128.0f, 128.0f, 128.0f, 128.0f, 128.0f, 128.0f, 128.0f};
#pragma unroll
    for (int x = 0; x < 8; ++x) {
        const float4 plo = lds4[b * STRIDE4 + x * 2 + 0];
        const float4 phi = lds4[b * STRIDE4 + x * 2 + 1];
        const float m = mu[x];
        O[0] = fmaf(m, plo.x, O[0]);
        O[1] = fmaf(m, plo.y, O[1]);
        O[2] = fmaf(m, plo.z, O[2]);
        O[3] = fmaf(m, plo.w, O[3]);
        O[4] = fmaf(m, phi.x, O[4]);
        O[5] = fmaf(m, phi.y, O[5]);
        O[6] = fmaf(m, phi.z, O[6]);
        O[7] = fmaf(m, phi.w, O[7]);
    }

    // ---- store my output row: coalesced, exact write traffic ----
    if (valid) {
        ((float4*)out)[base4 + 0] = make_float4(O[0], O[1], O[2], O[3]);
        ((float4*)out)[base4 + 1] = make_float4(O[4], O[5], O[6], O[7]);
    }
}

extern "C" void kernel_launch(void* const* d_in, const int* in_sizes, int n_in,
                              void* d_out, int out_size, void* d_ws, size_t ws_size,
                              hipStream_t stream) {
    const float* image = (const float*)d_in[0];
    const float* alpha = (const float*)d_in[1];
    const float* dct   = (const float*)d_in[2];
    float* outp = (float*)d_out;

    const int nblocks = in_sizes[0] / 64;
    const long long wgs = ((long long)nblocks + BPW - 1) / BPW;

    dct8x8_kernel<<<(int)wgs, WG, 0, stream>>>(image, alpha, dct, outp, nblocks);
}